// Round 21
// baseline (105.163 us; speedup 1.0000x reference)
//
#include <hip/hip_runtime.h>
#include <hip/hip_bf16.h>

// SubjectLayers via bf16 MFMA 32x32x16: out[b,o,t] = sum_c W[s,o,c]*x[b,c,t] + b[s,o]
// B=128, C=64, T=8192, S=16. fp32 in/out, bf16 matrix cores.
//
// R15 = R14 with the vmcnt bookkeeping fixed. R14's counted-vmcnt degenerated
// to a full drain because 40 W/bias VMEM ops (compiler-placed AFTER the DMAs)
// polluted the count: vmcnt(12) with ~56 outstanding = drain ~44 oldest.
// Fix (ordering made provable):
//   1) issue ALL W/bias loads FIRST (16+8 float4; bias as 8 broadcast float4
//      instead of 32 scalar loads) -> they are OLDER than every DMA
//   2) sched_barrier(0); issue 16 quarter-ordered gload_lds; sched_barrier(0)
//   3) quarter q: s_waitcnt vmcnt(12-4q) + s_barrier -> in-order retirement
//      guarantees W/bias + Q0..q DMAs retired, Q(q+1..) still in flight
// Compute/store per quarter unchanged from R12/R14 (frag cvt reads, 4 MFMAs,
// clean full-line direct-acc stores at q==3).

typedef __attribute__((ext_vector_type(8))) short  bf16x8;   // 4 VGPRs
typedef __attribute__((ext_vector_type(16))) float f32x16;   // 16 VGPRs

namespace {
constexpr int Cdim  = 64;
constexpr int Tdim  = 8192;
constexpr int TT    = 256;        // t per block tile
constexpr int BLOCK = 256;        // 4 waves
}

static __device__ __forceinline__ short f2bf(float f) {
    return (short)__builtin_bit_cast(unsigned short, __float2bfloat16(f));
}

__global__ __launch_bounds__(BLOCK, 2)
void subject_layers_r15(const float* __restrict__ x,
                        const int*   __restrict__ subj,
                        const float* __restrict__ W,
                        const float* __restrict__ bias,
                        float*       __restrict__ out) {
    __shared__ float tile[Cdim * TT];   // 64 KB f32; written once by DMA

    const int b    = blockIdx.y;
    const int tb   = blockIdx.x;
    const int tid  = threadIdx.x;
    const int wave = tid >> 6;
    const int lane = tid & 63;
    const int hi   = lane >> 5;   // 0..1
    const int ln   = lane & 31;   // m/n index within 32-tile
    const int s    = subj[b];

    const size_t xbase = (size_t)b * Cdim * Tdim + (size_t)tb * TT;

    // ---- (1) issue ALL W/bias VMEM first (oldest in the vmem queue) ----
    // W raw: per (ot,kb): 8 consecutive floats at row ot*32+ln, col kb*16+hi*8
    float4 wraw[2][4][2];
    const float* Wb = W + (size_t)s * Cdim * Cdim;
    #pragma unroll
    for (int ot = 0; ot < 2; ++ot)
        #pragma unroll
        for (int kb = 0; kb < 4; ++kb) {
            const float* ap = Wb + (size_t)(ot * 32 + ln) * Cdim + kb * 16 + hi * 8;
            wraw[ot][kb][0] = *reinterpret_cast<const float4*>(ap);
            wraw[ot][kb][1] = *reinterpret_cast<const float4*>(ap + 4);
        }
    // bias raw: lane needs bb[ot*32 + 4*hi + {0..3,8..11,16..19,24..27}]
    float4 braw[2][4];
    const float* bb = bias + (size_t)s * Cdim;
    #pragma unroll
    for (int ot = 0; ot < 2; ++ot)
        #pragma unroll
        for (int gq = 0; gq < 4; ++gq)
            braw[ot][gq] = *reinterpret_cast<const float4*>(bb + ot * 32 + 4 * hi + gq * 8);

    __builtin_amdgcn_sched_barrier(0);

    // ---- (2) issue ALL staging DMA, quarter-ordered ----
    // quarter q rows: q*16 + g*4 + wave (g<4); one gload_lds = one 1KB row.
    #pragma unroll
    for (int q = 0; q < 4; ++q)
        #pragma unroll
        for (int g = 0; g < 4; ++g) {
            const int row = q * 16 + g * 4 + wave;
            __builtin_amdgcn_global_load_lds(
                (const __attribute__((address_space(1))) unsigned int*)
                    (x + xbase + (size_t)row * Tdim + lane * 4),
                (__attribute__((address_space(3))) unsigned int*)
                    (&tile[row * TT]),
                16, 0, 0);
        }

    __builtin_amdgcn_sched_barrier(0);

    // ---- convert W raws -> bf16 frags; bias raws -> acc init ----
    // (compiler's own counted waitcnt covers these reads without draining DMA)
    // A[m][k]: m = ln, k = kb*16 + hi*8 + j  (mirrored with B -> k-perm cancels)
    bf16x8 afrag[2][4];
    #pragma unroll
    for (int ot = 0; ot < 2; ++ot)
        #pragma unroll
        for (int kb = 0; kb < 4; ++kb) {
            const float4 a0 = wraw[ot][kb][0];
            const float4 a1 = wraw[ot][kb][1];
            bf16x8 f;
            f[0] = f2bf(a0.x); f[1] = f2bf(a0.y); f[2] = f2bf(a0.z); f[3] = f2bf(a0.w);
            f[4] = f2bf(a1.x); f[5] = f2bf(a1.y); f[6] = f2bf(a1.z); f[7] = f2bf(a1.w);
            afrag[ot][kb] = f;
        }
    // C/D: col = ln, row(reg r) = (r&3) + 8*(r>>2) + 4*hi  [m74/m101-verified]
    // r = (gq, i): row = i + 8*gq + 4*hi -> value braw[ot][gq][i]
    f32x16 acc[2][2];   // [st][ot]
    #pragma unroll
    for (int ot = 0; ot < 2; ++ot) {
        f32x16 bi;
        #pragma unroll
        for (int gq = 0; gq < 4; ++gq) {
            bi[gq * 4 + 0] = braw[ot][gq].x;
            bi[gq * 4 + 1] = braw[ot][gq].y;
            bi[gq * 4 + 2] = braw[ot][gq].z;
            bi[gq * 4 + 3] = braw[ot][gq].w;
        }
        acc[0][ot] = bi;
        acc[1][ot] = bi;
    }

    // ---- (3) quarter loop: counted-vmcnt barrier, compute quarter q ----
    float* ob = out + xbase;
    #pragma unroll
    for (int q = 0; q < 4; ++q) {
        // W/bias (older) + quarters 0..q retired; 12-4q younger DMAs in flight
        if (q == 0)      asm volatile("s_waitcnt vmcnt(12)" ::: "memory");
        else if (q == 1) asm volatile("s_waitcnt vmcnt(8)"  ::: "memory");
        else if (q == 2) asm volatile("s_waitcnt vmcnt(4)"  ::: "memory");
        else             asm volatile("s_waitcnt vmcnt(0)"  ::: "memory");
        __builtin_amdgcn_s_barrier();
        __builtin_amdgcn_sched_barrier(0);   // pin: no ds_read hoisted above

        // compute quarter q (kb = q): 2 t-steps x 2 o-tiles
        #pragma unroll
        for (int st = 0; st < 2; ++st) {
            const int col = wave * 64 + st * 32 + ln;
            bf16x8 f;
            #pragma unroll
            for (int j = 0; j < 8; ++j)
                f[j] = f2bf(tile[(q * 16 + hi * 8 + j) * TT + col]);
            #pragma unroll
            for (int ot = 0; ot < 2; ++ot)
                acc[st][ot] = __builtin_amdgcn_mfma_f32_32x32x16_bf16(
                    afrag[ot][q], f, acc[st][ot], 0, 0, 0);
        }

        // last quarter: stores direct from acc (2 rows x 128B full lines)
        if (q == 3) {
            #pragma unroll
            for (int st = 0; st < 2; ++st) {
                const int col = wave * 64 + st * 32 + ln;
                #pragma unroll
                for (int ot = 0; ot < 2; ++ot)
                    #pragma unroll
                    for (int r = 0; r < 16; ++r)
                        ob[(size_t)(ot * 32 + (r & 3) + 8 * (r >> 2) + 4 * hi) * Tdim + col]
                            = acc[st][ot][r];
            }
        }
    }
}

extern "C" void kernel_launch(void* const* d_in, const int* in_sizes, int n_in,
                              void* d_out, int out_size, void* d_ws, size_t ws_size,
                              hipStream_t stream) {
    const float* x    = (const float*)d_in[0];   // [B, C, T]
    const int*   subj = (const int*)  d_in[1];   // [B]
    const float* W    = (const float*)d_in[2];   // [S, C, C]
    const float* bias = (const float*)d_in[3];   // [S, C]
    float*       out  = (float*)d_out;           // [B, C, T]

    const int B = in_sizes[1];                   // 128
    dim3 grid(Tdim / TT, B);                     // (32, 128) = 4096 blocks
    dim3 block(BLOCK);
    hipLaunchKernelGGL(subject_layers_r15, grid, block, 0, stream,
                       x, subj, W, bias, out);
}

// Round 22
// 100.261 us; speedup vs baseline: 1.0489x; 1.0489x over previous
//
#include <hip/hip_runtime.h>
#include <hip/hip_bf16.h>

// SubjectLayers via bf16 MFMA 32x32x16: out[b,o,t] = sum_c W[s,o,c]*x[b,c,t] + b[s,o]
// B=128, C=64, T=8192, S=16. fp32 in/out, bf16 matrix cores.
//
// FINAL (= R12, best measured: 101.0us, 5.31 TB/s effective = 84.5% of D2D).
// Family search results: reg-T14 105.8 / counted-vmcnt 104.8-105.2 /
// full-drain 104.5 / THIS half-split 101.0. Structure:
//  - gload_lds 1KB-row staging (zero VGPR round trip)
//  - C-split double buffer: stage c0..31 -> bar -> {issue DMA c32..63,
//    MFMA K-half 0} -> bar -> {MFMA K-half 1 + direct-acc stores}
//  - 2 barriers only (4-barrier variants lose to sync overhead)
//  - stores direct from acc: 2 rows x 128B full lines (measured clean WRITE)
//  - 64KB LDS, 2 blocks/CU; absmax 0.03125 (bf16, threshold 0.117)

typedef __attribute__((ext_vector_type(8))) short  bf16x8;   // 4 VGPRs
typedef __attribute__((ext_vector_type(16))) float f32x16;   // 16 VGPRs

namespace {
constexpr int Cdim  = 64;
constexpr int Tdim  = 8192;
constexpr int TT    = 256;        // t per block tile
constexpr int BLOCK = 256;        // 4 waves
}

static __device__ __forceinline__ short f2bf(float f) {
    return (short)__builtin_bit_cast(unsigned short, __float2bfloat16(f));
}

__global__ __launch_bounds__(BLOCK, 2)
void subject_layers_r12(const float* __restrict__ x,
                        const int*   __restrict__ subj,
                        const float* __restrict__ W,
                        const float* __restrict__ bias,
                        float*       __restrict__ out) {
    __shared__ float tA[32 * TT];   // c-rows 0..31  (32 KB)
    __shared__ float tB[32 * TT];   // c-rows 32..63 (32 KB)

    const int b    = blockIdx.y;
    const int tb   = blockIdx.x;
    const int tid  = threadIdx.x;
    const int wave = tid >> 6;
    const int lane = tid & 63;
    const int hi   = lane >> 5;   // 0..1
    const int ln   = lane & 31;   // m/n index within 32-tile
    const int s    = subj[b];

    const size_t xbase = (size_t)b * Cdim * Tdim + (size_t)tb * TT;

    // ---- stage K-half 0 (c-rows 0..31): wave w owns rows g*4+w, g<8;
    //      one global_load_lds = one 1KB row burst ----
    #pragma unroll
    for (int g = 0; g < 8; ++g) {
        const int row = g * 4 + wave;
        __builtin_amdgcn_global_load_lds(
            (const __attribute__((address_space(1))) unsigned int*)
                (x + xbase + (size_t)row * Tdim + lane * 4),
            (__attribute__((address_space(3))) unsigned int*)
                (&tA[row * TT]),
            16, 0, 0);
    }

    // ---- A fragments: W[s] -> bf16 (independent of staging) ----
    // A[m][k]: m = ln, k = kb*16 + hi*8 + j  (mirrored with B -> k-perm cancels)
    bf16x8 afrag[2][4];
    const float* Wb = W + (size_t)s * Cdim * Cdim;
    #pragma unroll
    for (int ot = 0; ot < 2; ++ot) {
        #pragma unroll
        for (int kb = 0; kb < 4; ++kb) {
            const float* ap = Wb + (size_t)(ot * 32 + ln) * Cdim + kb * 16 + hi * 8;
            const float4 a0 = *reinterpret_cast<const float4*>(ap);
            const float4 a1 = *reinterpret_cast<const float4*>(ap + 4);
            bf16x8 f;
            f[0] = f2bf(a0.x); f[1] = f2bf(a0.y); f[2] = f2bf(a0.z); f[3] = f2bf(a0.w);
            f[4] = f2bf(a1.x); f[5] = f2bf(a1.y); f[6] = f2bf(a1.z); f[7] = f2bf(a1.w);
            afrag[ot][kb] = f;
        }
    }

    // ---- bias -> accumulator init ----
    // C/D: col = ln, row(reg r) = (r&3) + 8*(r>>2) + 4*hi   [m74/m101-verified]
    f32x16 acc[2][2];   // [st][ot], live across bar2
    {
        const float* bb = bias + (size_t)s * Cdim;
        #pragma unroll
        for (int ot = 0; ot < 2; ++ot) {
            f32x16 bi;
            #pragma unroll
            for (int r = 0; r < 16; ++r)
                bi[r] = bb[ot * 32 + (r & 3) + 8 * (r >> 2) + 4 * hi];
            acc[0][ot] = bi;
            acc[1][ot] = bi;
        }
    }

    __syncthreads();   // K-half 0 staged (vmcnt drained)

    // ---- issue DMA for K-half 1 (c-rows 32..63) — flies during half-0 MFMA ----
    #pragma unroll
    for (int g = 0; g < 8; ++g) {
        const int row = 32 + g * 4 + wave;
        __builtin_amdgcn_global_load_lds(
            (const __attribute__((address_space(1))) unsigned int*)
                (x + xbase + (size_t)row * Tdim + lane * 4),
            (__attribute__((address_space(3))) unsigned int*)
                (&tB[(row - 32) * TT]),
            16, 0, 0);
    }

    // ---- K-half 0 compute: kb = 0,1 from tA ----
    #pragma unroll
    for (int st = 0; st < 2; ++st) {
        const int col = wave * 64 + st * 32 + ln;
        bf16x8 bfrag[2];
        #pragma unroll
        for (int kb = 0; kb < 2; ++kb) {
            bf16x8 f;
            #pragma unroll
            for (int j = 0; j < 8; ++j)
                f[j] = f2bf(tA[(kb * 16 + hi * 8 + j) * TT + col]);
            bfrag[kb] = f;
        }
        #pragma unroll
        for (int ot = 0; ot < 2; ++ot) {
            acc[st][ot] = __builtin_amdgcn_mfma_f32_32x32x16_bf16(
                afrag[ot][0], bfrag[0], acc[st][ot], 0, 0, 0);
            acc[st][ot] = __builtin_amdgcn_mfma_f32_32x32x16_bf16(
                afrag[ot][1], bfrag[1], acc[st][ot], 0, 0, 0);
        }
    }

    __syncthreads();   // K-half 1 staged

    // ---- K-half 1 compute (kb = 2,3 from tB) + direct-acc stores ----
    float* ob = out + xbase;
    #pragma unroll
    for (int st = 0; st < 2; ++st) {
        const int col = wave * 64 + st * 32 + ln;
        bf16x8 bfrag[2];
        #pragma unroll
        for (int kb = 0; kb < 2; ++kb) {
            bf16x8 f;
            #pragma unroll
            for (int j = 0; j < 8; ++j)
                f[j] = f2bf(tB[(kb * 16 + hi * 8 + j) * TT + col]);
            bfrag[kb] = f;
        }
        #pragma unroll
        for (int ot = 0; ot < 2; ++ot) {
            acc[st][ot] = __builtin_amdgcn_mfma_f32_32x32x16_bf16(
                afrag[ot][2], bfrag[0], acc[st][ot], 0, 0, 0);
            acc[st][ot] = __builtin_amdgcn_mfma_f32_32x32x16_bf16(
                afrag[ot][3], bfrag[1], acc[st][ot], 0, 0, 0);
            // store instr r: 2 rows x 128B full aligned lines (measured clean)
            #pragma unroll
            for (int r = 0; r < 16; ++r)
                ob[(size_t)(ot * 32 + (r & 3) + 8 * (r >> 2) + 4 * hi) * Tdim + col]
                    = acc[st][ot][r];
        }
    }
}

extern "C" void kernel_launch(void* const* d_in, const int* in_sizes, int n_in,
                              void* d_out, int out_size, void* d_ws, size_t ws_size,
                              hipStream_t stream) {
    const float* x    = (const float*)d_in[0];   // [B, C, T]
    const int*   subj = (const int*)  d_in[1];   // [B]
    const float* W    = (const float*)d_in[2];   // [S, C, C]
    const float* bias = (const float*)d_in[3];   // [S, C]
    float*       out  = (float*)d_out;           // [B, C, T]

    const int B = in_sizes[1];                   // 128
    dim3 grid(Tdim / TT, B);                     // (32, 128) = 4096 blocks
    dim3 block(BLOCK);
    hipLaunchKernelGGL(subject_layers_r12, grid, block, 0, stream,
                       x, subj, W, bias, out);
}